// Round 2
// baseline (228.635 us; speedup 1.0000x reference)
//
#include <hip/hip_runtime.h>
#include <hip/hip_bf16.h>

typedef __hip_bfloat16 bf16;
typedef __bf16 b16x8 __attribute__((ext_vector_type(8)));
typedef float f32x4 __attribute__((ext_vector_type(4)));
typedef float f32x2 __attribute__((ext_vector_type(2)));

#define HWs   12800   // 80*160
#define NPIX  25600   // 2*80*160
#define IMG_H 80
#define IMG_W 160

// load 8 consecutive f32 weights, convert to bf16 fragment (RTNE, same as k_prep did)
static __device__ inline b16x8 ldw8(const float* __restrict__ p)
{
    f32x4 a = *(const f32x4*)p;
    f32x4 c = *(const f32x4*)(p + 4);
    b16x8 r;
    r[0] = (__bf16)a[0]; r[1] = (__bf16)a[1]; r[2] = (__bf16)a[2]; r[3] = (__bf16)a[3];
    r[4] = (__bf16)c[0]; r[5] = (__bf16)c[1]; r[6] = (__bf16)c[2]; r[7] = (__bf16)c[3];
    return r;
}

// match-branch concatenated weight row: wc(0-71) | wg(72-143) | kpc(144-152) | kpg(153-161)
static __device__ inline const float* mat_row(
    const float* __restrict__ wc, const float* __restrict__ wg,
    const float* __restrict__ kpc, const float* __restrict__ kpg, int o)
{
    o = min(o, 161);                       // pad rows clamp (outputs discarded)
    if (o < 72)  return wc  + (size_t)o * 128;
    if (o < 144) return wg  + (size_t)(o - 72) * 128;
    if (o < 153) return kpc + (size_t)(o - 144) * 128;
    return kpg + (size_t)(o - 153) * 128;
}

// ---------------- Stage 1: fused LN + GEMMs (weights converted in-block) ----------------
// Runs concurrent with the harness 256MiB poison fill -> memory-starved but VALU-free;
// all stores are LDS-staged into coalesced 16B segments to minimize contention.
__global__ __launch_bounds__(256) void k_stage1(
    const float* __restrict__ match, const float* __restrict__ context, const float* __restrict__ geometric,
    const float* __restrict__ ln_g, const float* __restrict__ ln_b,
    const float* __restrict__ lnc_g, const float* __restrict__ lnc_b,
    const float* __restrict__ lng_g, const float* __restrict__ lng_b,
    const float* __restrict__ vc_w, const float* __restrict__ vg_w,
    const float* __restrict__ vc_b, const float* __restrict__ vg_b,
    const float* __restrict__ wc_w, const float* __restrict__ wg_w,
    const float* __restrict__ kpc_w, const float* __restrict__ kpg_w,
    const float* __restrict__ wc_b, const float* __restrict__ wg_b,
    const float* __restrict__ kpc_b, const float* __restrict__ kpg_b,
    const float* __restrict__ anc_c, const float* __restrict__ anc_g,
    unsigned char* __restrict__ ctx8, unsigned char* __restrict__ geo8,
    bf16* __restrict__ wts_g, float* __restrict__ kp_out)
{
    __shared__ __align__(16) bf16 tile_s[32 * 136];           // 8704 B
    __shared__ __align__(16) char u_s[32 * 152 * 2];          // 9728 B: logit_s / red / fp8 tile
    __shared__ float offs_s[32 * 18];                          // 2304 B
    __shared__ float bias_s[176];                              //  704 B   (21440 total)

    bf16* logit_s = (bf16*)u_s;                                // seg2: 32 x 152 logits
    float (*red1)[32] = (float(*)[32])u_s;                     // LN phase only
    float (*red2)[32] = (float(*)[32])(u_s + 1024);
    unsigned char* fp8_s = (unsigned char*)u_s;                // seg<2: 32 x 128 fp8 tile

    int bx = blockIdx.x;
    int seg = bx % 3;                    // 0 ctx, 1 geo, 2 match
    int tile = bx / 3;
    int t = threadIdx.x;
    int pixbase = tile * 32;

    const float* X  = (seg == 0) ? context : (seg == 1) ? geometric : match;
    const float* gg = (seg == 0) ? lnc_g   : (seg == 1) ? lng_g     : ln_g;
    const float* bb = (seg == 0) ? lnc_b   : (seg == 1) ? lng_b     : ln_b;

    // ---- issue LN global loads FIRST (oldest in vmcnt queue) ----
    int p = t & 31;
    int cq = t >> 5;
    int b = pixbase >= HWs;
    int hw = pixbase - b * HWs;
    const float* base = X + ((size_t)b * 128) * HWs + hw + p;
    float xv[16];
#pragma unroll
    for (int j = 0; j < 16; j++) xv[j] = base[(size_t)(cq * 16 + j) * HWs];

    // ---- prefetch + convert this wave's W-fragments (independent of LN) ----
    int wv = t >> 6;
    int lane = t & 63;
    int s = wv >> 1;                     // subtile of 16 pixels
    int h = wv & 1;                      // output-tile parity
    int lrow = lane & 15;
    int lq = lane >> 4;
    b16x8 wf[4][4];
#pragma unroll
    for (int i = 0; i < 4; i++) {
        int o = (h + 2 * i) * 16 + lrow;                        // < 128 always
        const float* wr = (seg == 0) ? vc_w + (size_t)o * 128
                        : (seg == 1) ? vg_w + (size_t)o * 128
                        : (o < 72)   ? wc_w + (size_t)o * 128
                                     : wg_w + (size_t)(o - 72) * 128;
#pragma unroll
        for (int kk = 0; kk < 4; kk++)
            wf[i][kk] = ldw8(wr + (kk * 4 + lq) * 8);
    }

    // ---- seg2 bias table ----
    if (seg == 2 && t < 176) {
        float v = 0.f;
        if (t < 72)       v = wc_b[t];
        else if (t < 144) v = wg_b[t - 72];
        else if (t < 153) v = kpc_b[t - 144];
        else if (t < 162) v = kpg_b[t - 153];
        bias_s[t] = v;
    }

    // ---- LN reduce + normalized tile ----
    {
        float s1 = 0.f, s2 = 0.f;
#pragma unroll
        for (int j = 0; j < 16; j++) { s1 += xv[j]; s2 += xv[j] * xv[j]; }
        red1[cq][p] = s1; red2[cq][p] = s2;
        __syncthreads();
        float S1 = 0.f, S2 = 0.f;
#pragma unroll
        for (int q = 0; q < 8; q++) { S1 += red1[q][p]; S2 += red2[q][p]; }
        float mean = S1 * (1.f / 128.f);
        float var  = fmaxf(S2 * (1.f / 128.f) - mean * mean, 0.f);
        float rstd = rsqrtf(var + 1e-5f);
#pragma unroll
        for (int j = 0; j < 16; j++) {
            int c = cq * 16 + j;
            float y = (xv[j] - mean) * rstd * gg[c] + bb[c];
            tile_s[p * 136 + c] = __float2bfloat16(y);
        }
        __syncthreads();                 // after this, u_s is free for logits / fp8 tile
    }

    // ---- A fragments (normalized pixels) ----
    const b16x8* arow = (const b16x8*)(tile_s + (s * 16 + lrow) * 136);
    b16x8 af[4];
#pragma unroll
    for (int kk = 0; kk < 4; kk++) af[kk] = arow[kk * 4 + lq];

    int prow = s * 16 + lrow;            // this lane's pixel (C/D column after operand swap)

    if (seg < 2) {
        unsigned char* val = (seg == 0) ? ctx8 : geo8;
        const float* vb = (seg == 0) ? vc_b : vg_b;
        int swz = (prow & 7) << 4;       // 16B-unit XOR swizzle breaks stride-128 bank conflict
#pragma unroll
        for (int i = 0; i < 4; i++) {
            int obase = (h + 2 * i) * 16 + lq * 4;              // 4 consecutive channels
            f32x4 acc = {0.f, 0.f, 0.f, 0.f};
#pragma unroll
            for (int kk = 0; kk < 4; kk++)
                acc = __builtin_amdgcn_mfma_f32_16x16x32_bf16(wf[i][kk], af[kk], acc, 0, 0, 0);
            f32x4 bv = *(const f32x4*)(vb + obase);
            int u = __builtin_amdgcn_cvt_pk_fp8_f32(acc[0] + bv[0], acc[1] + bv[1], 0, false);
            u = __builtin_amdgcn_cvt_pk_fp8_f32(acc[2] + bv[2], acc[3] + bv[3], u, true);
            *(unsigned int*)(fp8_s + prow * 128 + (obase ^ swz)) = (unsigned int)u;
        }
        __syncthreads();
        // coalesced copy-out: one uint4/thread, 1KB contiguous per wave
        int row = t >> 3;
        int col = t & 7;
        uint4 v4 = *(const uint4*)(fp8_s + row * 128 + ((col ^ (row & 7)) * 16));
        *(uint4*)(val + (size_t)(pixbase + row) * 128 + col * 16) = v4;
        return;
    }

    // ---- seg == 2: match branch ----
#pragma unroll
    for (int i = 0; i < 4; i++) {
        int obase = (h + 2 * i) * 16 + lq * 4;
        f32x4 acc = {0.f, 0.f, 0.f, 0.f};
#pragma unroll
        for (int kk = 0; kk < 4; kk++)
            acc = __builtin_amdgcn_mfma_f32_16x16x32_bf16(wf[i][kk], af[kk], acc, 0, 0, 0);
        f32x4 bv = *(const f32x4*)(bias_s + obase);
#pragma unroll
        for (int r = 0; r < 4; r++)
            logit_s[prow * 152 + obase + r] = __float2bfloat16(acc[r] + bv[r]);
    }
    for (int ot = h + 8; ot < 11; ot += 2) {        // h=0: 8,10 ; h=1: 9
        int obase = ot * 16 + lq * 4;
        const float* wr = mat_row(wc_w, wg_w, kpc_w, kpg_w, ot * 16 + lrow);
        f32x4 acc = {0.f, 0.f, 0.f, 0.f};
#pragma unroll
        for (int kk = 0; kk < 4; kk++)
            acc = __builtin_amdgcn_mfma_f32_16x16x32_bf16(ldw8(wr + (kk * 4 + lq) * 8), af[kk], acc, 0, 0, 0);
        f32x4 bv = *(const f32x4*)(bias_s + obase);
        if (ot == 8) {                              // o in [128,144) -> logits
#pragma unroll
            for (int r = 0; r < 4; r++)
                logit_s[prow * 152 + obase + r] = __float2bfloat16(acc[r] + bv[r]);
        } else if (ot == 9) {                       // o in [144,160) -> offsets 0..15
#pragma unroll
            for (int r = 0; r < 4; r++)
                offs_s[prow * 18 + (obase - 144) + r] = acc[r] + bv[r];
        } else {                                    // ot == 10: only o=160,161 valid
            if (lq == 0) {
                offs_s[prow * 18 + 16] = acc[0] + bv[0];
                offs_s[prow * 18 + 17] = acc[1] + bv[1];
            }
        }
    }
    __syncthreads();

    // softmax over P per (pixel, branch, group): 512 tasks, results kept in regs
    float sm[2][9];
#pragma unroll
    for (int i = 0; i < 2; i++) {
        int task = t + 256 * i;
        int lp = task >> 4;
        int sub = task & 15;
        int br = sub >> 3;
        int g = sub & 7;
        const bf16* basel = logit_s + lp * 152 + br * 72 + g;   // channel c = p*8+g
        float v[9];
        float m = -1e30f;
#pragma unroll
        for (int pp = 0; pp < 9; pp++) { v[pp] = __bfloat162float(basel[pp * 8]); m = fmaxf(m, v[pp]); }
        float ssum = 0.f;
#pragma unroll
        for (int pp = 0; pp < 9; pp++) { v[pp] = __expf(v[pp] - m); ssum += v[pp]; }
        float inv = 1.f / ssum;
#pragma unroll
        for (int pp = 0; pp < 9; pp++) sm[i][pp] = v[pp] * inv;
    }
    __syncthreads();                     // all logit reads complete
#pragma unroll
    for (int i = 0; i < 2; i++) {
        int task = t + 256 * i;
        int lp = task >> 4;
        int sub = task & 15;
        int br = sub >> 3;
        int g = sub & 7;
        bf16* dst = logit_s + lp * 152 + br * 72 + g * 9;       // stage [lp][br*72+g*9+pp]
#pragma unroll
        for (int pp = 0; pp < 9; pp++) dst[pp] = __float2bfloat16(sm[i][pp]);
    }
    __syncthreads();
    // coalesced wts store: block region = 64 tasks x 72 bf16 = 9216 B contiguous
#pragma unroll
    for (int i = 0; i < 3; i++) {
        int idx = t + 256 * i;
        if (idx < 576) {
            int lp = idx / 18;
            int c8 = idx - lp * 18;
            *(b16x8*)(wts_g + (size_t)pixbase * 144 + (size_t)idx * 8) =
                *(const b16x8*)(logit_s + lp * 152 + c8 * 8);
        }
    }

    // keypoints: 576 tasks (kp_out f32 = ref output dtype; k_fuse re-derives coords)
    for (int i = 0; i < 3; i++) {
        int task = t + 256 * i;
        if (task < 576) {
            int lp = task / 18;
            int sub2 = task - lp * 18;
            int br = sub2 / 9;
            int pp = sub2 - br * 9;
            int pix = pixbase + lp;
            float off = offs_s[lp * 18 + br * 9 + pp];
            const float* anc = br ? anc_g : anc_c;
            f32x2 a2 = *(const f32x2*)(anc + (size_t)pix * 18 + pp * 2);
            f32x2 kp2 = {a2[0] + off, a2[1]};
            *(f32x2*)(kp_out + (size_t)br * (NPIX * 18) + (size_t)pix * 18 + pp * 2) = kp2;
        }
    }
}

// ---------------- fused bilinear gather (fp8) + aggregate + output projection ----------------
// 1600 blocks x 16 pixels. 8 lanes per (pixel,branch) task, 16 channels (= one group) each:
// halves the redundant per-lane coordinate math vs 16-lane tasks, same 128B line traffic.
// Coords re-derived from kp_out (coords_g eliminated). out_w converted from f32 in-block.
__global__ __launch_bounds__(256) void k_fuse(
    const unsigned char* __restrict__ ctx8, const unsigned char* __restrict__ geo8,
    const bf16* __restrict__ wts_g, const float* __restrict__ kp_out,
    const float* __restrict__ mask,
    const float* __restrict__ out_w, const float* __restrict__ out_b,
    float* __restrict__ out)
{
    __shared__ __align__(16) bf16 agg_s[16 * 264];   // stride 264: bank-spread for b128 r/w

    int t = threadIdx.x;
    int wv = t >> 6;
    int lane = t & 63;
    int task = wv * 8 + (lane >> 3);     // 0..31
    int br = task >> 4;                  // waves 0,1 -> ctx ; 2,3 -> geo
    int pixidx = task & 15;
    int g = lane & 7;                    // group; lane owns channels [g*16, g*16+16)
    int c0 = g * 16;

    int pixbase = blockIdx.x * 16;       // 1600 blocks; never straddles batch
    int pix = pixbase + pixidx;
    int b = pixbase >= HWs;
    int rowbase = b * HWs;

    const unsigned char* val = br ? geo8 : ctx8;
    const bf16* wb = wts_g + (size_t)(pix * 2 + br) * 72 + g * 9;
    const float* cb = kp_out + (size_t)br * (NPIX * 18) + (size_t)pix * 18;

    float wtv[9];
#pragma unroll
    for (int pp = 0; pp < 9; pp++) wtv[pp] = __bfloat162float(wb[pp]);

    float acc[16];
#pragma unroll
    for (int j = 0; j < 16; j++) acc[j] = 0.f;

#pragma unroll
    for (int pp = 0; pp < 9; pp++) {
        f32x2 kp2 = *(const f32x2*)(cb + pp * 2);
        float px = kp2[0] * 160.f - 0.5f;            // identical arithmetic to old coords_g
        float py = kp2[1] * 80.f - 0.5f;
        float fx = floorf(px), fy = floorf(py);
        float dx = px - fx, dy = py - fy;
        int x0 = (int)fx, y0 = (int)fy;
        float wt = wtv[pp];
#pragma unroll
        for (int c4 = 0; c4 < 4; c4++) {
            int xi = x0 + (c4 & 1);
            int yi = y0 + (c4 >> 1);
            bool ok = (xi >= 0) & (xi < IMG_W) & (yi >= 0) & (yi < IMG_H);
            int xc = min(max(xi, 0), IMG_W - 1);
            int yc = min(max(yi, 0), IMG_H - 1);
            float wx = (c4 & 1) ? dx : 1.f - dx;
            float wy = (c4 >> 1) ? dy : 1.f - dy;
            float wgt = ok ? wx * wy * wt : 0.f;
            uint4 u = *(const uint4*)(val + (size_t)(rowbase + yc * IMG_W + xc) * 128 + c0);
            unsigned int uw[4] = {u.x, u.y, u.z, u.w};
#pragma unroll
            for (int w2 = 0; w2 < 4; w2++) {
                f32x2 lo = __builtin_amdgcn_cvt_pk_f32_fp8(uw[w2], false);
                f32x2 hi = __builtin_amdgcn_cvt_pk_f32_fp8(uw[w2], true);
                acc[w2 * 4 + 0] += wgt * lo[0];
                acc[w2 * 4 + 1] += wgt * lo[1];
                acc[w2 * 4 + 2] += wgt * hi[0];
                acc[w2 * 4 + 3] += wgt * hi[1];
            }
        }
    }
    float mv = br ? 1.f : mask[pix];
    b16x8 pk0, pk1;
#pragma unroll
    for (int j = 0; j < 8; j++) {
        pk0[j] = (__bf16)(acc[j] * mv);
        pk1[j] = (__bf16)(acc[8 + j] * mv);
    }
    *(b16x8*)(agg_s + pixidx * 264 + br * 128 + c0) = pk0;
    *(b16x8*)(agg_s + pixidx * 264 + br * 128 + c0 + 8) = pk1;
    __syncthreads();

    // ---- projection: 16 pix x 128 out, K=256 (out_w f32 -> bf16 in-flight) ----
    int lrow = lane & 15;
    int lq = lane >> 4;
    b16x8 af[8];
#pragma unroll
    for (int kk = 0; kk < 8; kk++)
        af[kk] = *(const b16x8*)(agg_s + lrow * 264 + (kk * 4 + lq) * 8);
#pragma unroll
    for (int i = 0; i < 2; i++) {
        int o = (wv + 4 * i) * 16 + lrow;
        const float* wrow = out_w + (size_t)o * 256;
        f32x4 acc4 = {0.f, 0.f, 0.f, 0.f};
#pragma unroll
        for (int kk = 0; kk < 8; kk++)
            acc4 = __builtin_amdgcn_mfma_f32_16x16x32_bf16(af[kk], ldw8(wrow + (kk * 4 + lq) * 8), acc4, 0, 0, 0);
        float bias = out_b[o];
        f32x4 st;
#pragma unroll
        for (int r = 0; r < 4; r++) st[r] = acc4[r] + bias;
        int hw0 = pixbase + lq * 4 - rowbase;       // pix = pixbase + lq*4 + r -> consecutive hw
        *(f32x4*)(out + (size_t)b * (128 * HWs) + (size_t)o * HWs + hw0) = st;
    }
}

extern "C" void kernel_launch(void* const* d_in, const int* in_sizes, int n_in,
                              void* d_out, int out_size, void* d_ws, size_t ws_size,
                              hipStream_t stream)
{
    const float* mask      = (const float*)d_in[0];
    const float* match     = (const float*)d_in[1];
    const float* context   = (const float*)d_in[2];
    const float* geometric = (const float*)d_in[3];
    const float* anc_c     = (const float*)d_in[4];
    const float* anc_g     = (const float*)d_in[5];
    const float* ln_g  = (const float*)d_in[6];
    const float* ln_b  = (const float*)d_in[7];
    const float* lnc_g = (const float*)d_in[8];
    const float* lnc_b = (const float*)d_in[9];
    const float* lng_g = (const float*)d_in[10];
    const float* lng_b = (const float*)d_in[11];
    const float* wc_w  = (const float*)d_in[12];
    const float* wc_b  = (const float*)d_in[13];
    const float* wg_w  = (const float*)d_in[14];
    const float* wg_b  = (const float*)d_in[15];
    const float* vc_w  = (const float*)d_in[16];
    const float* vc_b  = (const float*)d_in[17];
    const float* vg_w  = (const float*)d_in[18];
    const float* vg_b  = (const float*)d_in[19];
    const float* out_w = (const float*)d_in[20];
    const float* out_b = (const float*)d_in[21];
    const float* kpc_w = (const float*)d_in[22];
    const float* kpc_b = (const float*)d_in[23];
    const float* kpg_w = (const float*)d_in[24];
    const float* kpg_b = (const float*)d_in[25];

    // d_ws layout
    char* w = (char*)d_ws;
    unsigned char* ctx8 = (unsigned char*)(w);            //  3,276,800 B (fp8)
    unsigned char* geo8 = (unsigned char*)(w + 3276800);  //  3,276,800 B
    bf16*  wts_g    = (bf16*)(w + 6553600);               //  7,372,800 B

    float* outp = (float*)d_out;
    float* kp_out = outp + (size_t)2 * 128 * HWs;         // outputs are f32 (ref dtype)

    k_stage1<<<2400, 256, 0, stream>>>(match, context, geometric,
                                       ln_g, ln_b, lnc_g, lnc_b, lng_g, lng_b,
                                       vc_w, vg_w, vc_b, vg_b,
                                       wc_w, wg_w, kpc_w, kpg_w,
                                       wc_b, wg_b, kpc_b, kpg_b,
                                       anc_c, anc_g,
                                       ctx8, geo8, wts_g, kp_out);
    k_fuse<<<1600, 256, 0, stream>>>(ctx8, geo8, wts_g, kp_out, mask,
                                     out_w, out_b, outp);
}